// Round 3
// baseline (27642.349 us; speedup 1.0000x reference)
//
#include <hip/hip_runtime.h>
#include <hip/hip_bf16.h>
#include <math.h>

// LSTM (N=64, T=1024, D=H=512) via bf16 MFMA.
// prep_wt: Wt[col][k] bf16 (2048 x 1024) in ws = [Wx;Wh] transposed.  (4 MB)
// lstm_step: one launch per t. 64 blocks x 512 thr (8 waves).
//   Block tile: all 64 batch rows x 32 cols (4 gates x 8 j), j0 = blk*8.
//   Wave (rowg = w&3, colg = w>>2): one 16x16 C tile, K=1024 -> 32 MFMA.
//   A-frag: fp32 x / h_prev loaded as 2x float4, converted in-lane to bf16.
//   B-frag: 16B load from Wt.
// c_state: fp32 in ws after Wt (128 KB). h_prev read from out[:, t-1, :].

#define TT 1024
#define HH 512
#define FH 2048
#define KK 1024

typedef __attribute__((ext_vector_type(8))) short bf16x8;
typedef __attribute__((ext_vector_type(4))) float f32x4;

__device__ __forceinline__ unsigned short f2bf(float f) {
    return __builtin_bit_cast(unsigned short, __float2bfloat16(f));
}

__global__ __launch_bounds__(256)
void prep_wt(const float* __restrict__ Wx, const float* __restrict__ Wh,
             unsigned short* __restrict__ Wt)
{
    __shared__ float tile[64][65];
    const int c0  = blockIdx.x * 64;   // col tile
    const int k0  = blockIdx.y * 64;   // k tile
    const int tid = threadIdx.x;

    #pragma unroll
    for (int it = 0; it < 16; ++it) {
        int idx = it * 256 + tid;
        int kk = idx >> 6, cc = idx & 63;
        int k = k0 + kk;
        float w = (k < 512) ? Wx[(size_t)k * FH + c0 + cc]
                            : Wh[(size_t)(k - 512) * FH + c0 + cc];
        tile[kk][cc] = w;
    }
    __syncthreads();

    #pragma unroll
    for (int it = 0; it < 8; ++it) {
        int idx = it * 256 + tid;
        int cc = idx >> 5, kp = idx & 31;
        unsigned int lo = f2bf(tile[kp * 2][cc]);
        unsigned int hi = f2bf(tile[kp * 2 + 1][cc]);
        *(unsigned int*)(Wt + (size_t)(c0 + cc) * KK + k0 + kp * 2) =
            lo | (hi << 16);
    }
}

__global__ __launch_bounds__(512)
void lstm_step(const float* __restrict__ x,
               const float* __restrict__ h0,
               const unsigned short* __restrict__ Wt,
               const float* __restrict__ b,
               float* __restrict__ out,
               float* __restrict__ c_state,
               int t)
{
    __shared__ float As[64][33];

    const int tid  = threadIdx.x;
    const int wv   = tid >> 6;
    const int lane = tid & 63;
    const int rowg = wv & 3;          // M tile (batch rows 16*rowg..)
    const int colg = wv >> 2;         // 0..1 (cols 16*colg..)
    const int j0   = blockIdx.x * 8;

    const int l15  = lane & 15;
    const int ksub = (lane >> 4) * 8;

    const int lc   = colg * 16 + l15;      // local col 0..31
    const int gate = lc >> 3;
    const int jj   = lc & 7;
    const int gcol = gate * HH + j0 + jj;  // global col in [0,2048)

    const int m = rowg * 16 + l15;         // batch row 0..63

    const unsigned short* wt = Wt + (size_t)gcol * KK + ksub;
    const float* xr = x + ((size_t)m * TT + t) * 512 + ksub;
    const float* hr = (t == 0) ? (h0 + (size_t)m * HH + ksub)
                               : (out + ((size_t)m * TT + (t - 1)) * HH + ksub);

    f32x4 acc = {0.f, 0.f, 0.f, 0.f};

    #pragma unroll
    for (int ks = 0; ks < 16; ++ks) {          // x part: k = ks*32 + ksub + e
        float4 u = *(const float4*)(xr + ks * 32);
        float4 v = *(const float4*)(xr + ks * 32 + 4);
        bf16x8 a;
        a[0] = (short)f2bf(u.x); a[1] = (short)f2bf(u.y);
        a[2] = (short)f2bf(u.z); a[3] = (short)f2bf(u.w);
        a[4] = (short)f2bf(v.x); a[5] = (short)f2bf(v.y);
        a[6] = (short)f2bf(v.z); a[7] = (short)f2bf(v.w);
        bf16x8 bb = *(const bf16x8*)(wt + ks * 32);
        acc = __builtin_amdgcn_mfma_f32_16x16x32_bf16(a, bb, acc, 0, 0, 0);
    }
    #pragma unroll
    for (int ks = 0; ks < 16; ++ks) {          // h part: k = 512 + ks*32 + ksub + e
        float4 u = *(const float4*)(hr + ks * 32);
        float4 v = *(const float4*)(hr + ks * 32 + 4);
        bf16x8 a;
        a[0] = (short)f2bf(u.x); a[1] = (short)f2bf(u.y);
        a[2] = (short)f2bf(u.z); a[3] = (short)f2bf(u.w);
        a[4] = (short)f2bf(v.x); a[5] = (short)f2bf(v.y);
        a[6] = (short)f2bf(v.z); a[7] = (short)f2bf(v.w);
        bf16x8 bb = *(const bf16x8*)(wt + 512 + ks * 32);
        acc = __builtin_amdgcn_mfma_f32_16x16x32_bf16(a, bb, acc, 0, 0, 0);
    }

    // C frag: col = lane&15 (+colbase), row = (lane>>4)*4 + r (+rowbase)
    #pragma unroll
    for (int r = 0; r < 4; ++r)
        As[rowg * 16 + (lane >> 4) * 4 + r][lc] = acc[r];

    __syncthreads();

    // gate phase: 512 cells = 64 rows x 8 j
    {
        int n = tid >> 3;
        int q = tid & 7;
        float Ai = As[n][q]      + b[j0 + q];
        float Af = As[n][8 + q]  + b[HH + j0 + q];
        float Ao = As[n][16 + q] + b[2 * HH + j0 + q];
        float Ag = As[n][24 + q] + b[3 * HH + j0 + q];

        float c_old = (t == 0) ? 0.f : c_state[(size_t)n * HH + j0 + q];

        float ig = 1.f / (1.f + __expf(-Ai));
        float fg = 1.f / (1.f + __expf(-Af));
        float og = 1.f / (1.f + __expf(-Ao));
        float gg = tanhf(Ag);

        float cn = fg * c_old + ig * gg;
        float hn = og * tanhf(cn);

        c_state[(size_t)n * HH + j0 + q] = cn;
        out[((size_t)n * TT + t) * HH + j0 + q] = hn;
    }
}

extern "C" void kernel_launch(void* const* d_in, const int* in_sizes, int n_in,
                              void* d_out, int out_size, void* d_ws, size_t ws_size,
                              hipStream_t stream)
{
    const float* x  = (const float*)d_in[0];
    const float* h0 = (const float*)d_in[1];
    const float* Wx = (const float*)d_in[2];
    const float* Wh = (const float*)d_in[3];
    const float* b  = (const float*)d_in[4];
    float* out = (float*)d_out;

    unsigned short* Wt = (unsigned short*)d_ws;                    // 4 MB
    float* c_state = (float*)((char*)d_ws + (size_t)FH * KK * 2);  // 128 KB

    prep_wt<<<dim3(32, 16), 256, 0, stream>>>(Wx, Wh, Wt);
    for (int t = 0; t < TT; ++t) {
        lstm_step<<<64, 512, 0, stream>>>(x, h0, Wt, b, out, c_state, t);
    }
}